// Round 4
// baseline (387.982 us; speedup 1.0000x reference)
//
#include <hip/hip_runtime.h>
#include <hip/hip_bf16.h>
#include <math.h>

typedef __attribute__((ext_vector_type(8))) short short8;
typedef __attribute__((ext_vector_type(4))) float f32x4;
typedef __attribute__((ext_vector_type(2))) unsigned int uint2v;

#define DEVINL static __device__ __forceinline__

// B=4096, NE=64, DE=96, NA=8, NACT=16, DH=256, NH=4, HD=64, OD=64

// ---- workspace layout (bf16 elements) ----
static constexpr int WE_OFF  = 0;        // K=96  N=256 frags  (24576)
static constexpr int MQK_OFF = 24576;    // 4 x [256x256] frags (4*65536)
static constexpr int WV_OFF  = 286720;   // K=256 N=256
static constexpr int WO_OFF  = 352256;
static constexpr int WM1_OFF = 417792;
static constexpr int WM2_OFF = 483328;   // K=256 N=64
static constexpr int WL1_OFF = 499712;
static constexpr int WL2_OFF = 565248;   // ends 581632
static constexpr int ATTN_OFF = 581632;  // attn buffer: 4096*8*256 bf16 (16MB)

// ---- front kernel LDS (dynamic, 81920 B = 80KB -> 2 blocks/CU) ----
static constexpr int XOFF   = 0;       // X [64][256] bf16 swz, stride 512 (32K)
static constexpr int VTOFF  = 32768;   // vT [256][64] bf16 swz, stride 128 (32K)
static constexpr int EOFF   = 65536;   // E [64][96] (12288) -> t [4][8][256] (16K) -> w [4][8][64] (4K)
static constexpr int ACTOFF = 77824;   // 8 ints (past E, inside 16K region)
static constexpr int LDS_F  = 81920;

// ---- back kernel LDS ----
static constexpr int B_AT = 0;       // attn/m1/l1 [64][256] swz stride 512 (32K)
static constexpr int B_H  = 32768;   // hidden (32K)
static constexpr int B_EM = 65536;   // 64 ints
static constexpr int LDS_B = 65792;

DEVINL unsigned short f2bf(float f) {
  union { float f; unsigned u; } x; x.f = f;
  unsigned r = x.u + 0x7fffu + ((x.u >> 16) & 1u);
  return (unsigned short)(r >> 16);
}

DEVINL f32x4 mfma(short8 a, short8 b, f32x4 c) {
  return __builtin_amdgcn_mfma_f32_16x16x32_bf16(a, b, c, 0, 0, 0);
}

// B-fragment load from prepped weights: one coalesced 16B load per lane
DEVINL short8 ldfrag(const unsigned short* wf, int off, int nt, int kt, int nkt, int lane) {
  return *(const short8*)(wf + off + ((nt * nkt + kt) << 9) + (lane << 3));
}

// ---------- prep_frag: fp32 weights -> bf16 MFMA B-fragments ----------
// one thread = one fragment lane: 8 strided loads, one 16B contiguous store
__global__ __launch_bounds__(512) void prep_frag(
    const float* We, const float* Win, const float* Wout, const float* Wm1,
    const float* Wm2, const float* Wl1, const float* Wl2, unsigned short* wf) {
  const int m = blockIdx.y;
  const int Ks[7]  = {96, 256, 256, 256, 256, 256, 256};
  const int Ns[7]  = {256, 256, 256, 256, 64, 256, 64};
  const int ld_[7] = {256, 768, 256, 256, 64, 256, 64};
  const int co_[7] = {0, 512, 0, 0, 0, 0, 0};
  const int off[7] = {WE_OFF, WV_OFF, WO_OFF, WM1_OFF, WM2_OFF, WL1_OFF, WL2_OFF};
  const float* S[7] = {We, Win, Wout, Wm1, Wm2, Wl1, Wl2};
  const int K = Ks[m], N = Ns[m], nkt = K >> 5;
  const int fid = blockIdx.x * 512 + threadIdx.x;
  if (fid >= (N >> 4) * nkt * 64) return;
  const int lane = fid & 63;
  const int kt = (fid >> 6) % nkt;
  const int nt = fid / (nkt << 6);
  const int row0 = kt * 32 + ((lane >> 4) << 3);
  const int col = nt * 16 + (lane & 15);
  const float* sp = S[m] + (long)row0 * ld_[m] + co_[m] + col;
  const int ld = ld_[m];
  short8 s;
#pragma unroll
  for (int j = 0; j < 8; ++j) s[j] = (short)f2bf(sp[j * ld]);
  *(short8*)(wf + off[m] + fid * 8) = s;
}

// ---------- prep_mqk: M_h = Wq_h @ Wk_h^T -> bf16 fragments (MFMA) ----------
__global__ __launch_bounds__(1024) void prep_mqk(const float* __restrict__ Win,
                                                 unsigned short* __restrict__ wf) {
  __shared__ char smq[65536];   // WqL [256][64] bf16 swz + WkL
  const int h = blockIdx.x;
  const int tid = threadIdx.x;
  const int w = tid >> 6, lane = tid & 63, g = lane >> 4, c = lane & 15;
  {
    const int d = tid >> 2, hd0 = (tid & 3) * 16;
    const int sw = (d & 7) << 4;
#pragma unroll
    for (int mat = 0; mat < 2; ++mat) {
      const float* srcp = Win + (long)d * 768 + mat * 256 + h * 64 + hd0;
      short8 s0, s1;
#pragma unroll
      for (int j = 0; j < 8; ++j) s0[j] = (short)f2bf(srcp[j]);
#pragma unroll
      for (int j = 0; j < 8; ++j) s1[j] = (short)f2bf(srcp[8 + j]);
      char* base = smq + mat * 32768 + d * 128;
      *(short8*)(base + ((hd0 * 2) ^ sw)) = s0;
      *(short8*)(base + ((hd0 * 2 + 16) ^ sw)) = s1;
    }
  }
  __syncthreads();
#pragma unroll 4
  for (int mt = 0; mt < 16; ++mt) {
    f32x4 acc = {0.f, 0.f, 0.f, 0.f};
#pragma unroll
    for (int kt = 0; kt < 2; ++kt) {
      const int ra = mt * 16 + c;
      short8 a = *(const short8*)(smq + ra * 128 + ((kt * 64 + g * 16) ^ ((ra & 7) << 4)));
      const int rb = w * 16 + c;
      short8 b = *(const short8*)(smq + 32768 + rb * 128 + ((kt * 64 + g * 16) ^ ((rb & 7) << 4)));
      acc = mfma(a, b, acc);
    }
#pragma unroll
    for (int r = 0; r < 4; ++r) {
      const int d1 = mt * 16 + g * 4 + r;
      wf[MQK_OFF + h * 65536 + ((w * 8 + (d1 >> 5)) << 9) +
         ((((d1 >> 3) & 3) << 4) + c) * 8 + (d1 & 7)] = f2bf(acc[r]);
    }
  }
}

// ---------- front kernel: 1 item/block, 512 threads, 80KB LDS ----------
__global__ __launch_bounds__(512, 4) void front_kernel(
    const float* __restrict__ entities, const int* __restrict__ obs_mask,
    const float* __restrict__ acts, const float* __restrict__ Wa,
    const float* __restrict__ be, const unsigned short* __restrict__ wf,
    unsigned short* __restrict__ attn_g) {
  extern __shared__ char sm[];
  const int tid = threadIdx.x;
  const int w = tid >> 6, lane = tid & 63;
  const int g = lane >> 4, c = lane & 15;
  const long ig = blockIdx.x;

  // ---- ph0: entities -> E bf16 swz; action ids
  {
    const int row = tid >> 3, seg = tid & 7;
    const float* src = entities + ig * 6144 + row * 96 + seg * 12;
    const int ebase = EOFF + row * 192;
    const int sw = (row & 3) << 4;
#pragma unroll
    for (int p = 0; p < 3; ++p) {
      float4 f = *(const float4*)(src + p * 4);
      uint2v u;
      u.x = f2bf(f.x) | ((unsigned)f2bf(f.y) << 16);
      u.y = f2bf(f.z) | ((unsigned)f2bf(f.w) << 16);
      *(uint2v*)(sm + ebase + ((seg * 24 + p * 8) ^ sw)) = u;
    }
    if (tid < 8) {
      const float* oh = acts + (ig * 8 + tid) * 16;
      int id = 0;
#pragma unroll
      for (int a = 0; a < 16; ++a) if (oh[a] > 0.5f) id = a;
      ((int*)(sm + ACTOFF))[tid] = id;
    }
  }
  __syncthreads();

  // ---- ph1: x = relu(E@We + ha + be) -> X
  {
    f32x4 acc[4][2] = {};
#pragma unroll
    for (int kt = 0; kt < 3; ++kt) {
      short8 b0 = ldfrag(wf, WE_OFF, 2 * w, kt, 3, lane);
      short8 b1 = ldfrag(wf, WE_OFF, 2 * w + 1, kt, 3, lane);
#pragma unroll
      for (int mt = 0; mt < 4; ++mt) {
        const int row = mt * 16 + c;
        short8 a = *(const short8*)(sm + EOFF + row * 192 +
                                    ((kt * 64 + g * 16) ^ ((row & 3) << 4)));
        acc[mt][0] = mfma(a, b0, acc[mt][0]);
        acc[mt][1] = mfma(a, b1, acc[mt][1]);
      }
    }
#pragma unroll
    for (int n = 0; n < 2; ++n) {
      const int col = (2 * w + n) * 16 + c;
      const float bev = be[col];
#pragma unroll
      for (int mt = 0; mt < 4; ++mt)
#pragma unroll
        for (int r = 0; r < 4; ++r) {
          const int row = mt * 16 + g * 4 + r;
          float v = acc[mt][n][r] + bev;
          if (row < 8) {
            int id = ((const int*)(sm + ACTOFF))[row];
            v += Wa[id * 256 + col];
          }
          v = fmaxf(v, 0.f);
          *(unsigned short*)(sm + XOFF + row * 512 +
                             ((col * 2) ^ ((row & 7) << 4))) = f2bf(v);
        }
    }
  }
  __syncthreads();

  // ---- ph2: t_h = x[0:8] @ M_h  (M_h = Wq_h Wk_h^T) -> t (overlays E)
  {
    const int h = w >> 1;
    f32x4 ta[8] = {};
#pragma unroll
    for (int kt = 0; kt < 8; ++kt) {
      short8 a = *(const short8*)(sm + XOFF + (c & 7) * 512 +
                                  ((kt * 64 + g * 16) ^ ((c & 7) << 4)));
#pragma unroll
      for (int n = 0; n < 8; ++n) {
        short8 b = ldfrag(wf, MQK_OFF + h * 65536, (w & 1) * 8 + n, kt, 8, lane);
        ta[n] = mfma(a, b, ta[n]);
      }
    }
    if (g < 2) {
#pragma unroll
      for (int n = 0; n < 8; ++n) {
        const int nt = (w & 1) * 8 + n;
#pragma unroll
        for (int r = 0; r < 4; ++r) {
          const int q = g * 4 + r;
          const int col = nt * 16 + c;
          *(unsigned short*)(sm + EOFF + h * 4096 + q * 512 +
                             ((col * 2) ^ (q << 4))) = f2bf(ta[n][r]);
        }
      }
    }
  }
  __syncthreads();

  // ---- ph3: logits = t @ X^T, mask, softmax -> w (overlays t[0])
  {
    float wvals[4][4];
    const int h = w;
    if (w < 4) {
      f32x4 lac[4] = {};
#pragma unroll
      for (int kt = 0; kt < 8; ++kt) {
        short8 a = *(const short8*)(sm + EOFF + h * 4096 + (c & 7) * 512 +
                                    ((kt * 64 + g * 16) ^ ((c & 7) << 4)));
#pragma unroll
        for (int nt = 0; nt < 4; ++nt) {
          const int key = nt * 16 + c;
          short8 b = *(const short8*)(sm + XOFF + key * 512 +
                                      ((kt * 64 + g * 16) ^ ((key & 7) << 4)));
          lac[nt] = mfma(a, b, lac[nt]);
        }
      }
      if (g < 2) {
        const int* obs = obs_mask + ig * 4096;
#pragma unroll
        for (int r = 0; r < 4; ++r) {
          const int qi = g * 4 + r;
          float vals[4];
#pragma unroll
          for (int nt = 0; nt < 4; ++nt) {
            int msk = obs[qi * 64 + nt * 16 + c];
            vals[nt] = msk ? -INFINITY : lac[nt][r] * 0.125f;
          }
          float mx = fmaxf(fmaxf(vals[0], vals[1]), fmaxf(vals[2], vals[3]));
#pragma unroll
          for (int d = 1; d < 16; d <<= 1) mx = fmaxf(mx, __shfl_xor(mx, d, 64));
          float s = 0.f;
#pragma unroll
          for (int nt = 0; nt < 4; ++nt) {
            float e = (mx == -INFINITY) ? 0.f : __expf(vals[nt] - mx);
            vals[nt] = e; s += e;
          }
#pragma unroll
          for (int d = 1; d < 16; d <<= 1) s += __shfl_xor(s, d, 64);
          const float inv = (s > 0.f) ? 1.f / s : 0.f;
#pragma unroll
          for (int nt = 0; nt < 4; ++nt) wvals[r][nt] = vals[nt] * inv;
        }
      }
    }
    __syncthreads();   // all t reads done; w overlays t region
    if (w < 4 && g < 2) {
#pragma unroll
      for (int r = 0; r < 4; ++r) {
        const int qi = g * 4 + r;
#pragma unroll
        for (int nt = 0; nt < 4; ++nt) {
          const int key = nt * 16 + c;
          *(unsigned short*)(sm + EOFF + (h * 8 + qi) * 128 +
                             ((key * 2) ^ (qi << 4))) = f2bf(wvals[r][nt]);
        }
      }
    }
  }

  // ---- ph4: v = x @ Wv -> vT (packed b64); no barrier needed before (disjoint regions)
  {
    f32x4 acc[4][2] = {};
#pragma unroll
    for (int kt = 0; kt < 8; ++kt) {
      short8 b0 = ldfrag(wf, WV_OFF, 2 * w, kt, 8, lane);
      short8 b1 = ldfrag(wf, WV_OFF, 2 * w + 1, kt, 8, lane);
#pragma unroll
      for (int mt = 0; mt < 4; ++mt) {
        const int row = mt * 16 + c;
        short8 a = *(const short8*)(sm + XOFF + row * 512 +
                                    ((kt * 64 + g * 16) ^ ((row & 7) << 4)));
        acc[mt][0] = mfma(a, b0, acc[mt][0]);
        acc[mt][1] = mfma(a, b1, acc[mt][1]);
      }
    }
#pragma unroll
    for (int n = 0; n < 2; ++n) {
      const int col = (2 * w + n) * 16 + c;
#pragma unroll
      for (int mt = 0; mt < 4; ++mt) {
        unsigned long long pk = 0;
#pragma unroll
        for (int r = 0; r < 4; ++r)
          pk |= (unsigned long long)f2bf(acc[mt][n][r]) << (16 * r);
        *(unsigned long long*)(sm + VTOFF + col * 128 +
                               ((mt * 32 + g * 8) ^ ((col & 7) << 4))) = pk;
      }
    }
  }
  __syncthreads();

  // ---- ph5: attn = w @ vT per head -> global (pre-swizzled for back kernel)
  {
    f32x4 aac[2] = {};
#pragma unroll
    for (int e = 0; e < 2; ++e) {
      const int tt = w * 2 + e, h = tt >> 2, n2 = tt & 3;
#pragma unroll
      for (int kt = 0; kt < 2; ++kt) {
        short8 a = *(const short8*)(sm + EOFF + h * 1024 + (c & 7) * 128 +
                                    ((kt * 64 + g * 16) ^ ((c & 7) << 4)));
        const int vrow = h * 64 + n2 * 16 + c;
        short8 b = *(const short8*)(sm + VTOFF + vrow * 128 +
                                    ((kt * 64 + g * 16) ^ ((vrow & 7) << 4)));
        aac[e] = mfma(a, b, aac[e]);
      }
    }
    if (g < 2) {
#pragma unroll
      for (int e = 0; e < 2; ++e) {
        const int tt = w * 2 + e, h = tt >> 2, n2 = tt & 3;
#pragma unroll
        for (int r = 0; r < 4; ++r) {
          const int q = g * 4 + r;
          const int col = h * 64 + n2 * 16 + c;
          attn_g[(ig * 8 + q) * 256 + (col ^ (q << 3))] = f2bf(aac[e][r]);
        }
      }
    }
  }
}

// ---------- back kernel: batched MLP chain, 64 rows (8 items) per block ----------
__global__ __launch_bounds__(512, 4) void back_kernel(
    const int* __restrict__ entity_mask, const float* __restrict__ bout,
    const float* __restrict__ bm1, const float* __restrict__ bm2,
    const float* __restrict__ bl1, const float* __restrict__ bl2,
    const unsigned short* __restrict__ wf, const unsigned short* __restrict__ attn_g,
    float* __restrict__ out) {
  extern __shared__ char sm[];
  const int tid = threadIdx.x;
  const int w = tid >> 6, lane = tid & 63;
  const int g = lane >> 4, c = lane & 15;
  const long blk = blockIdx.x;

  // B1: stage attn (already swizzled in global) + entity masks
  {
    const uint4* src = (const uint4*)(attn_g + blk * 16384);
#pragma unroll
    for (int itr = 0; itr < 4; ++itr)
      *(uint4*)(sm + B_AT + itr * 8192 + tid * 16) = src[itr * 512 + tid];
    if (tid < 64)
      ((int*)(sm + B_EM))[tid] = entity_mask[(blk * 8 + (tid >> 3)) * 64 + (tid & 7)];
  }
  __syncthreads();

  // B2: hidden = mask/relu(attn @ Wout + bout) -> B_H
  {
    f32x4 acc[4][2] = {};
#pragma unroll
    for (int kt = 0; kt < 8; ++kt) {
      short8 b0 = ldfrag(wf, WO_OFF, 2 * w, kt, 8, lane);
      short8 b1 = ldfrag(wf, WO_OFF, 2 * w + 1, kt, 8, lane);
#pragma unroll
      for (int mt = 0; mt < 4; ++mt) {
        const int row = mt * 16 + c;
        short8 a = *(const short8*)(sm + B_AT + row * 512 +
                                    ((kt * 64 + g * 16) ^ ((row & 7) << 4)));
        acc[mt][0] = mfma(a, b0, acc[mt][0]);
        acc[mt][1] = mfma(a, b1, acc[mt][1]);
      }
    }
#pragma unroll
    for (int n = 0; n < 2; ++n) {
      const int col = (2 * w + n) * 16 + c;
      const float bo = bout[col];
#pragma unroll
      for (int mt = 0; mt < 4; ++mt)
#pragma unroll
        for (int r = 0; r < 4; ++r) {
          const int row = mt * 16 + g * 4 + r;
          const int em = ((const int*)(sm + B_EM))[row];
          float v = acc[mt][n][r] + bo;
          v = em ? 0.f : fmaxf(v, 0.f);
          *(unsigned short*)(sm + B_H + row * 512 +
                             ((col * 2) ^ ((row & 7) << 4))) = f2bf(v);
        }
    }
  }
  __syncthreads();

  // B3: m1 = relu(hidden @ Wm1 + bm1) -> B_AT (attn dead)
  {
    f32x4 acc[4][2] = {};
#pragma unroll
    for (int kt = 0; kt < 8; ++kt) {
      short8 b0 = ldfrag(wf, WM1_OFF, 2 * w, kt, 8, lane);
      short8 b1 = ldfrag(wf, WM1_OFF, 2 * w + 1, kt, 8, lane);
#pragma unroll
      for (int mt = 0; mt < 4; ++mt) {
        const int row = mt * 16 + c;
        short8 a = *(const short8*)(sm + B_H + row * 512 +
                                    ((kt * 64 + g * 16) ^ ((row & 7) << 4)));
        acc[mt][0] = mfma(a, b0, acc[mt][0]);
        acc[mt][1] = mfma(a, b1, acc[mt][1]);
      }
    }
#pragma unroll
    for (int n = 0; n < 2; ++n) {
      const int col = (2 * w + n) * 16 + c;
      const float bv = bm1[col];
#pragma unroll
      for (int mt = 0; mt < 4; ++mt)
#pragma unroll
        for (int r = 0; r < 4; ++r) {
          const int row = mt * 16 + g * 4 + r;
          float v = fmaxf(acc[mt][n][r] + bv, 0.f);
          *(unsigned short*)(sm + B_AT + row * 512 +
                             ((col * 2) ^ ((row & 7) << 4))) = f2bf(v);
        }
    }
  }
  __syncthreads();

  // B4: mean = m1 @ Wm2 + bm2 -> out
  {
    const int mh = w >> 2, nt = w & 3;
    f32x4 acc[2] = {};
#pragma unroll
    for (int kt = 0; kt < 8; ++kt) {
      short8 b = ldfrag(wf, WM2_OFF, nt, kt, 8, lane);
#pragma unroll
      for (int m2 = 0; m2 < 2; ++m2) {
        const int row = (mh * 2 + m2) * 16 + c;
        short8 a = *(const short8*)(sm + B_AT + row * 512 +
                                    ((kt * 64 + g * 16) ^ ((row & 7) << 4)));
        acc[m2] = mfma(a, b, acc[m2]);
      }
    }
    const float bv = bm2[nt * 16 + c];
#pragma unroll
    for (int m2 = 0; m2 < 2; ++m2)
#pragma unroll
      for (int r = 0; r < 4; ++r) {
        const int row = (mh * 2 + m2) * 16 + g * 4 + r;
        out[(blk * 8 + (row >> 3)) * 512 + (row & 7) * 64 + nt * 16 + c] = acc[m2][r] + bv;
      }
  }
  __syncthreads();

  // B5: l1 = relu(hidden @ Wl1 + bl1) -> B_AT (m1 dead)
  {
    f32x4 acc[4][2] = {};
#pragma unroll
    for (int kt = 0; kt < 8; ++kt) {
      short8 b0 = ldfrag(wf, WL1_OFF, 2 * w, kt, 8, lane);
      short8 b1 = ldfrag(wf, WL1_OFF, 2 * w + 1, kt, 8, lane);
#pragma unroll
      for (int mt = 0; mt < 4; ++mt) {
        const int row = mt * 16 + c;
        short8 a = *(const short8*)(sm + B_H + row * 512 +
                                    ((kt * 64 + g * 16) ^ ((row & 7) << 4)));
        acc[mt][0] = mfma(a, b0, acc[mt][0]);
        acc[mt][1] = mfma(a, b1, acc[mt][1]);
      }
    }
#pragma unroll
    for (int n = 0; n < 2; ++n) {
      const int col = (2 * w + n) * 16 + c;
      const float bv = bl1[col];
#pragma unroll
      for (int mt = 0; mt < 4; ++mt)
#pragma unroll
        for (int r = 0; r < 4; ++r) {
          const int row = mt * 16 + g * 4 + r;
          float v = fmaxf(acc[mt][n][r] + bv, 0.f);
          *(unsigned short*)(sm + B_AT + row * 512 +
                             ((col * 2) ^ ((row & 7) << 4))) = f2bf(v);
        }
    }
  }
  __syncthreads();

  // B6: logvar = clip(l1 @ Wl2 + bl2, -10, 0) -> out
  {
    const int mh = w >> 2, nt = w & 3;
    f32x4 acc[2] = {};
#pragma unroll
    for (int kt = 0; kt < 8; ++kt) {
      short8 b = ldfrag(wf, WL2_OFF, nt, kt, 8, lane);
#pragma unroll
      for (int m2 = 0; m2 < 2; ++m2) {
        const int row = (mh * 2 + m2) * 16 + c;
        short8 a = *(const short8*)(sm + B_AT + row * 512 +
                                    ((kt * 64 + g * 16) ^ ((row & 7) << 4)));
        acc[m2] = mfma(a, b, acc[m2]);
      }
    }
    const float bv = bl2[nt * 16 + c];
#pragma unroll
    for (int m2 = 0; m2 < 2; ++m2)
#pragma unroll
      for (int r = 0; r < 4; ++r) {
        const int row = (mh * 2 + m2) * 16 + g * 4 + r;
        float v = acc[m2][r] + bv;
        v = fminf(fmaxf(v, -10.f), 0.f);
        out[2097152 + (blk * 8 + (row >> 3)) * 512 + (row & 7) * 64 + nt * 16 + c] = v;
      }
  }
}

extern "C" void kernel_launch(void* const* d_in, const int* in_sizes, int n_in,
                              void* d_out, int out_size, void* d_ws, size_t ws_size,
                              hipStream_t stream) {
  const float* entities    = (const float*)d_in[0];
  const int*   entity_mask = (const int*)d_in[1];
  const int*   obs_mask    = (const int*)d_in[2];
  const float* acts        = (const float*)d_in[3];
  const float* We   = (const float*)d_in[4];
  const float* be   = (const float*)d_in[5];
  const float* Wa   = (const float*)d_in[6];
  const float* Win  = (const float*)d_in[7];
  const float* Wout = (const float*)d_in[8];
  const float* bout = (const float*)d_in[9];
  const float* Wm1  = (const float*)d_in[10];
  const float* bm1  = (const float*)d_in[11];
  const float* Wm2  = (const float*)d_in[12];
  const float* bm2  = (const float*)d_in[13];
  const float* Wl1  = (const float*)d_in[14];
  const float* bl1  = (const float*)d_in[15];
  const float* Wl2  = (const float*)d_in[16];
  const float* bl2  = (const float*)d_in[17];
  unsigned short* wf = (unsigned short*)d_ws;
  unsigned short* attn_g = wf + ATTN_OFF;

  prep_frag<<<dim3(16, 7), 512, 0, stream>>>(We, Win, Wout, Wm1, Wm2, Wl1, Wl2, wf);
  prep_mqk<<<4, 1024, 0, stream>>>(Win, wf);

  hipFuncSetAttribute((const void*)front_kernel,
                      hipFuncAttributeMaxDynamicSharedMemorySize, LDS_F);
  hipFuncSetAttribute((const void*)back_kernel,
                      hipFuncAttributeMaxDynamicSharedMemorySize, LDS_B);

  front_kernel<<<4096, 512, LDS_F, stream>>>(entities, obs_mask, acts, Wa, be, wf, attn_g);
  back_kernel<<<512, 512, LDS_B, stream>>>(entity_mask, bout, bm1, bm2, bl1, bl2,
                                           wf, attn_g, (float*)d_out);
}

// Round 6
// 337.350 us; speedup vs baseline: 1.1501x; 1.1501x over previous
//
#include <hip/hip_runtime.h>
#include <hip/hip_bf16.h>
#include <math.h>

typedef __attribute__((ext_vector_type(8))) short short8;
typedef __attribute__((ext_vector_type(4))) float f32x4;
typedef __attribute__((ext_vector_type(2))) unsigned int uint2v;

#define DEVINL static __device__ __forceinline__

// B=4096, NE=64, DE=96, NA=8, NACT=16, DH=256, NH=4, HD=64, OD=64

// ---- workspace layout (bf16 elements) ----
static constexpr int WE_OFF  = 0;        // K=96  N=256 (24576)
static constexpr int WQ_OFF  = 24576;    // K=256 N=256 (65536)
static constexpr int WKT_OFF = 90112;    // per-head Wk^T: [h][nt16][kt2][lane][8] (65536)
static constexpr int WV_OFF  = 155648;   // K=256 N=256
static constexpr int WO_OFF  = 221184;
static constexpr int WM1_OFF = 286720;
static constexpr int WM2_OFF = 352256;   // K=256 N=64
static constexpr int WL1_OFF = 368640;
static constexpr int WL2_OFF = 434176;   // ends 450560
static constexpr int ATTN_OFF = 450560;  // attn buffer: 4096*8*256 bf16 (16MB)

// ---- front kernel LDS (dynamic, 81920 B = 80KB -> 2 blocks/CU) ----
static constexpr int XOFF   = 0;       // X [64][256] bf16 swz, stride 512 (32K)
static constexpr int VTOFF  = 32768;   // vT [256][64] bf16 swz, stride 128 (32K)
static constexpr int EOFF   = 65536;   // E [64][96] (12K) -> t [4][8][256] (16K) -> w [4][8][64] (4K)
static constexpr int QO     = 77824;   // q [8][256] stride 512 (4K); overlays acts after ph1
static constexpr int ACTOFF = 77824;   // 8 ints (dead before q written)
static constexpr int LDS_F  = 81920;

// ---- back kernel LDS ----
static constexpr int B_AT = 0;       // attn/m1/l1 [64][256] swz stride 512 (32K)
static constexpr int B_H  = 32768;   // hidden (32K)
static constexpr int B_EM = 65536;   // 64 ints
static constexpr int LDS_B = 65792;

DEVINL unsigned short f2bf(float f) {
  __hip_bfloat16 h = __float2bfloat16(f);
  return __builtin_bit_cast(unsigned short, h);
}

DEVINL f32x4 mfma(short8 a, short8 b, f32x4 c) {
  return __builtin_amdgcn_mfma_f32_16x16x32_bf16(a, b, c, 0, 0, 0);
}

// B-fragment load from prepped weights: one coalesced 16B load per lane
DEVINL short8 ldfrag(const unsigned short* wf, int off, int nt, int kt, int nkt, int lane) {
  return *(const short8*)(wf + off + ((nt * nkt + kt) << 9) + (lane << 3));
}

// ---------- prep_frag: fp32 weights -> bf16 MFMA B-fragments ----------
// one thread = one fragment lane: 8 strided (or contiguous) loads, one 16B store
__global__ __launch_bounds__(512) void prep_frag(
    const float* We, const float* Win, const float* Wout, const float* Wm1,
    const float* Wm2, const float* Wl1, const float* Wl2, unsigned short* wf) {
  const int m = blockIdx.y;
  const int fid = blockIdx.x * 512 + threadIdx.x;
  if (m == 2) {  // WKT: per-head Wk^T as B-frags, n=dh(256), k=head-dim(64)
    if (fid >= 8192) return;
    const int lane = fid & 63;
    const int kt = (fid >> 6) & 1;
    const int nt = (fid >> 7) & 15;
    const int h  = fid >> 11;
    const int d  = nt * 16 + (lane & 15);
    const float* sp = Win + (long)d * 768 + 256 + h * 64 + kt * 32 + ((lane >> 4) << 3);
    short8 s;
#pragma unroll
    for (int j = 0; j < 8; ++j) s[j] = (short)f2bf(sp[j]);
    *(short8*)(wf + WKT_OFF + fid * 8) = s;
    return;
  }
  const int Ks[9]  = {96, 256, 0, 256, 256, 256, 256, 256, 256};
  const int Ns[9]  = {256, 256, 0, 256, 256, 256, 64, 256, 64};
  const int ld_[9] = {256, 768, 0, 768, 256, 256, 64, 256, 64};
  const int co_[9] = {0, 0, 0, 512, 0, 0, 0, 0, 0};
  const int off[9] = {WE_OFF, WQ_OFF, 0, WV_OFF, WO_OFF, WM1_OFF, WM2_OFF, WL1_OFF, WL2_OFF};
  const float* S[9] = {We, Win, Win, Win, Wout, Wm1, Wm2, Wl1, Wl2};
  const int K = Ks[m], N = Ns[m], nkt = K >> 5;
  if (fid >= (N >> 4) * nkt * 64) return;
  const int lane = fid & 63;
  const int kt = (fid >> 6) % nkt;
  const int nt = fid / (nkt << 6);
  const int row0 = kt * 32 + ((lane >> 4) << 3);
  const int col = nt * 16 + (lane & 15);
  const float* sp = S[m] + (long)row0 * ld_[m] + co_[m] + col;
  const int ld = ld_[m];
  short8 s;
#pragma unroll
  for (int j = 0; j < 8; ++j) s[j] = (short)f2bf(sp[j * ld]);
  *(short8*)(wf + off[m] + fid * 8) = s;
}

// ---------- front kernel: 1 item/block, 512 threads, 80KB LDS ----------
__global__ __launch_bounds__(512, 4) void front_kernel(
    const float* __restrict__ entities, const int* __restrict__ obs_mask,
    const float* __restrict__ acts, const float* __restrict__ Wa,
    const float* __restrict__ be, const unsigned short* __restrict__ wf,
    unsigned short* __restrict__ attn_g) {
  extern __shared__ char sm[];
  const int tid = threadIdx.x;
  const int w = tid >> 6, lane = tid & 63;
  const int g = lane >> 4, c = lane & 15;
  const long ig = blockIdx.x;

  // obs_mask prefetch for the softmax lanes (used in ph4)
  int obsv[16];
  if (w < 4 && g < 2) {
    const int* obs = obs_mask + ig * 4096;
#pragma unroll
    for (int r = 0; r < 4; ++r)
#pragma unroll
      for (int nt = 0; nt < 4; ++nt)
        obsv[r * 4 + nt] = obs[(g * 4 + r) * 64 + nt * 16 + c];
  }

  // ---- ph0: entities -> E bf16 swz; action ids
  {
    const int row = tid >> 3, seg = tid & 7;
    const float* src = entities + ig * 6144 + row * 96 + seg * 12;
    const int ebase = EOFF + row * 192;
    const int sw = (row & 3) << 4;
#pragma unroll
    for (int p = 0; p < 3; ++p) {
      float4 f = *(const float4*)(src + p * 4);
      uint2v u;
      u.x = f2bf(f.x) | ((unsigned)f2bf(f.y) << 16);
      u.y = f2bf(f.z) | ((unsigned)f2bf(f.w) << 16);
      *(uint2v*)(sm + ebase + ((seg * 24 + p * 8) ^ sw)) = u;
    }
    if (tid < 8) {
      const float* oh = acts + (ig * 8 + tid) * 16;
      int id = 0;
#pragma unroll
      for (int a = 0; a < 16; ++a) if (oh[a] > 0.5f) id = a;
      ((int*)(sm + ACTOFF))[tid] = id;
    }
  }
  __syncthreads();

  // Wa prefetch (actids now visible); hides under ph1 MFMA
  float wav[4][2] = {};
  if (g < 2) {
#pragma unroll
    for (int r = 0; r < 4; ++r) {
      const int id = ((const int*)(sm + ACTOFF))[g * 4 + r];
      wav[r][0] = Wa[id * 256 + (2 * w) * 16 + c];
      wav[r][1] = Wa[id * 256 + (2 * w + 1) * 16 + c];
    }
  }

  // ---- ph1: x = relu(E@We + ha + be) -> X
  {
    f32x4 acc[4][2] = {};
#pragma unroll
    for (int kt = 0; kt < 3; ++kt) {
      short8 b0 = ldfrag(wf, WE_OFF, 2 * w, kt, 3, lane);
      short8 b1 = ldfrag(wf, WE_OFF, 2 * w + 1, kt, 3, lane);
#pragma unroll
      for (int mt = 0; mt < 4; ++mt) {
        const int row = mt * 16 + c;
        short8 a = *(const short8*)(sm + EOFF + row * 192 +
                                    ((kt * 64 + g * 16) ^ ((row & 3) << 4)));
        acc[mt][0] = mfma(a, b0, acc[mt][0]);
        acc[mt][1] = mfma(a, b1, acc[mt][1]);
      }
    }
#pragma unroll
    for (int n = 0; n < 2; ++n) {
      const int col = (2 * w + n) * 16 + c;
      const float bev = be[col];
#pragma unroll
      for (int mt = 0; mt < 4; ++mt)
#pragma unroll
        for (int r = 0; r < 4; ++r) {
          const int row = mt * 16 + g * 4 + r;
          float v = acc[mt][n][r] + bev;
          if (row < 8) v += wav[r][n];
          v = fmaxf(v, 0.f);
          *(unsigned short*)(sm + XOFF + row * 512 +
                             ((col * 2) ^ ((row & 7) << 4))) = f2bf(v);
        }
    }
  }
  __syncthreads();

  // ---- ph2: q = x[0:8] @ Wq -> q_lds (overlays dead acts)
  {
    f32x4 qa[2] = {};
#pragma unroll
    for (int kt = 0; kt < 8; ++kt) {
      short8 b0 = ldfrag(wf, WQ_OFF, 2 * w, kt, 8, lane);
      short8 b1 = ldfrag(wf, WQ_OFF, 2 * w + 1, kt, 8, lane);
      short8 a = *(const short8*)(sm + XOFF + (c & 7) * 512 +
                                  ((kt * 64 + g * 16) ^ ((c & 7) << 4)));
      qa[0] = mfma(a, b0, qa[0]);
      qa[1] = mfma(a, b1, qa[1]);
    }
    if (g < 2) {
#pragma unroll
      for (int n = 0; n < 2; ++n) {
        const int col = (2 * w + n) * 16 + c;
#pragma unroll
        for (int r = 0; r < 4; ++r) {
          const int qi = g * 4 + r;
          *(unsigned short*)(sm + QO + qi * 512 +
                             ((col * 2) ^ (qi << 4))) = f2bf(qa[n][r]);
        }
      }
    }
  }
  __syncthreads();

  // ---- ph3: t_h = q_h @ Wk_h^T -> t (overlays E+q after in-phase barrier)
  {
    const int h = w >> 1, hf = w & 1;
    f32x4 ta[8] = {};
#pragma unroll
    for (int kt = 0; kt < 2; ++kt) {
      short8 a = *(const short8*)(sm + QO + (c & 7) * 512 +
                                  ((h * 128 + kt * 64 + g * 16) ^ ((c & 7) << 4)));
#pragma unroll
      for (int n = 0; n < 8; ++n) {
        short8 b = ldfrag(wf, WKT_OFF, h * 16 + hf * 8 + n, kt, 2, lane);
        ta[n] = mfma(a, b, ta[n]);
      }
    }
    __syncthreads();  // all q reads done before t overwrites the region
    if (g < 2) {
#pragma unroll
      for (int n = 0; n < 8; ++n) {
        const int col = (hf * 8 + n) * 16 + c;
#pragma unroll
        for (int r = 0; r < 4; ++r) {
          const int qi = g * 4 + r;
          *(unsigned short*)(sm + EOFF + h * 4096 + qi * 512 +
                             ((col * 2) ^ (qi << 4))) = f2bf(ta[n][r]);
        }
      }
    }
  }
  __syncthreads();

  // ---- ph4: logits = t @ X^T, mask, softmax -> w (overlays t[0])
  {
    float wvals[4][4];
    const int h = w;
    if (w < 4) {
      f32x4 lac[4] = {};
#pragma unroll
      for (int kt = 0; kt < 8; ++kt) {
        short8 a = *(const short8*)(sm + EOFF + h * 4096 + (c & 7) * 512 +
                                    ((kt * 64 + g * 16) ^ ((c & 7) << 4)));
#pragma unroll
        for (int nt = 0; nt < 4; ++nt) {
          const int key = nt * 16 + c;
          short8 b = *(const short8*)(sm + XOFF + key * 512 +
                                      ((kt * 64 + g * 16) ^ ((key & 7) << 4)));
          lac[nt] = mfma(a, b, lac[nt]);
        }
      }
      if (g < 2) {
#pragma unroll
        for (int r = 0; r < 4; ++r) {
          float vals[4];
#pragma unroll
          for (int nt = 0; nt < 4; ++nt)
            vals[nt] = obsv[r * 4 + nt] ? -INFINITY : lac[nt][r] * 0.125f;
          float mx = fmaxf(fmaxf(vals[0], vals[1]), fmaxf(vals[2], vals[3]));
#pragma unroll
          for (int d = 1; d < 16; d <<= 1) mx = fmaxf(mx, __shfl_xor(mx, d, 64));
          float s = 0.f;
#pragma unroll
          for (int nt = 0; nt < 4; ++nt) {
            float e = (mx == -INFINITY) ? 0.f : __expf(vals[nt] - mx);
            vals[nt] = e; s += e;
          }
#pragma unroll
          for (int d = 1; d < 16; d <<= 1) s += __shfl_xor(s, d, 64);
          const float inv = (s > 0.f) ? 1.f / s : 0.f;
#pragma unroll
          for (int nt = 0; nt < 4; ++nt) wvals[r][nt] = vals[nt] * inv;
        }
      }
    }
    __syncthreads();   // all t reads done; w overlays t region
    if (w < 4 && g < 2) {
#pragma unroll
      for (int r = 0; r < 4; ++r) {
        const int qi = g * 4 + r;
#pragma unroll
        for (int nt = 0; nt < 4; ++nt) {
          const int key = nt * 16 + c;
          *(unsigned short*)(sm + EOFF + (h * 8 + qi) * 128 +
                             ((key * 2) ^ (qi << 4))) = f2bf(wvals[r][nt]);
        }
      }
    }
  }

  // ---- ph5: v = x @ Wv -> vT (packed b64); disjoint regions, no pre-barrier
  {
    f32x4 acc[4][2] = {};
#pragma unroll
    for (int kt = 0; kt < 8; ++kt) {
      short8 b0 = ldfrag(wf, WV_OFF, 2 * w, kt, 8, lane);
      short8 b1 = ldfrag(wf, WV_OFF, 2 * w + 1, kt, 8, lane);
#pragma unroll
      for (int mt = 0; mt < 4; ++mt) {
        const int row = mt * 16 + c;
        short8 a = *(const short8*)(sm + XOFF + row * 512 +
                                    ((kt * 64 + g * 16) ^ ((row & 7) << 4)));
        acc[mt][0] = mfma(a, b0, acc[mt][0]);
        acc[mt][1] = mfma(a, b1, acc[mt][1]);
      }
    }
#pragma unroll
    for (int n = 0; n < 2; ++n) {
      const int col = (2 * w + n) * 16 + c;
#pragma unroll
      for (int mt = 0; mt < 4; ++mt) {
        unsigned long long pk = 0;
#pragma unroll
        for (int r = 0; r < 4; ++r)
          pk |= (unsigned long long)f2bf(acc[mt][n][r]) << (16 * r);
        *(unsigned long long*)(sm + VTOFF + col * 128 +
                               ((mt * 32 + g * 8) ^ ((col & 7) << 4))) = pk;
      }
    }
  }
  __syncthreads();

  // ---- ph6: attn = w @ vT per head -> global (pre-swizzled for back kernel)
  {
    f32x4 aac[2] = {};
#pragma unroll
    for (int e = 0; e < 2; ++e) {
      const int tt = w * 2 + e, h = tt >> 2, n2 = tt & 3;
#pragma unroll
      for (int kt = 0; kt < 2; ++kt) {
        short8 a = *(const short8*)(sm + EOFF + h * 1024 + (c & 7) * 128 +
                                    ((kt * 64 + g * 16) ^ ((c & 7) << 4)));
        const int vrow = h * 64 + n2 * 16 + c;
        short8 b = *(const short8*)(sm + VTOFF + vrow * 128 +
                                    ((kt * 64 + g * 16) ^ ((vrow & 7) << 4)));
        aac[e] = mfma(a, b, aac[e]);
      }
    }
    if (g < 2) {
#pragma unroll
      for (int e = 0; e < 2; ++e) {
        const int tt = w * 2 + e, h = tt >> 2, n2 = tt & 3;
#pragma unroll
        for (int r = 0; r < 4; ++r) {
          const int q = g * 4 + r;
          const int col = h * 64 + n2 * 16 + c;
          attn_g[(ig * 8 + q) * 256 + (col ^ (q << 3))] = f2bf(aac[e][r]);
        }
      }
    }
  }
}

// ---------- back kernel: batched MLP chain, 64 rows (8 items) per block ----------
__global__ __launch_bounds__(512, 4) void back_kernel(
    const int* __restrict__ entity_mask, const float* __restrict__ bout,
    const float* __restrict__ bm1, const float* __restrict__ bm2,
    const float* __restrict__ bl1, const float* __restrict__ bl2,
    const unsigned short* __restrict__ wf, const unsigned short* __restrict__ attn_g,
    float* __restrict__ out) {
  extern __shared__ char sm[];
  const int tid = threadIdx.x;
  const int w = tid >> 6, lane = tid & 63;
  const int g = lane >> 4, c = lane & 15;
  const long blk = blockIdx.x;

  // B1: stage attn (already swizzled in global) + entity masks
  {
    const uint4* src = (const uint4*)(attn_g + blk * 16384);
#pragma unroll
    for (int itr = 0; itr < 4; ++itr)
      *(uint4*)(sm + B_AT + itr * 8192 + tid * 16) = src[itr * 512 + tid];
    if (tid < 64)
      ((int*)(sm + B_EM))[tid] = entity_mask[(blk * 8 + (tid >> 3)) * 64 + (tid & 7)];
  }
  __syncthreads();

  // B2: hidden = mask/relu(attn @ Wout + bout) -> B_H
  {
    f32x4 acc[4][2] = {};
#pragma unroll
    for (int kt = 0; kt < 8; ++kt) {
      short8 b0 = ldfrag(wf, WO_OFF, 2 * w, kt, 8, lane);
      short8 b1 = ldfrag(wf, WO_OFF, 2 * w + 1, kt, 8, lane);
#pragma unroll
      for (int mt = 0; mt < 4; ++mt) {
        const int row = mt * 16 + c;
        short8 a = *(const short8*)(sm + B_AT + row * 512 +
                                    ((kt * 64 + g * 16) ^ ((row & 7) << 4)));
        acc[mt][0] = mfma(a, b0, acc[mt][0]);
        acc[mt][1] = mfma(a, b1, acc[mt][1]);
      }
    }
#pragma unroll
    for (int n = 0; n < 2; ++n) {
      const int col = (2 * w + n) * 16 + c;
      const float bo = bout[col];
#pragma unroll
      for (int mt = 0; mt < 4; ++mt)
#pragma unroll
        for (int r = 0; r < 4; ++r) {
          const int row = mt * 16 + g * 4 + r;
          const int em = ((const int*)(sm + B_EM))[row];
          float v = acc[mt][n][r] + bo;
          v = em ? 0.f : fmaxf(v, 0.f);
          *(unsigned short*)(sm + B_H + row * 512 +
                             ((col * 2) ^ ((row & 7) << 4))) = f2bf(v);
        }
    }
  }
  __syncthreads();

  // B3: m1 = relu(hidden @ Wm1 + bm1) -> B_AT (attn dead)
  {
    f32x4 acc[4][2] = {};
#pragma unroll
    for (int kt = 0; kt < 8; ++kt) {
      short8 b0 = ldfrag(wf, WM1_OFF, 2 * w, kt, 8, lane);
      short8 b1 = ldfrag(wf, WM1_OFF, 2 * w + 1, kt, 8, lane);
#pragma unroll
      for (int mt = 0; mt < 4; ++mt) {
        const int row = mt * 16 + c;
        short8 a = *(const short8*)(sm + B_H + row * 512 +
                                    ((kt * 64 + g * 16) ^ ((row & 7) << 4)));
        acc[mt][0] = mfma(a, b0, acc[mt][0]);
        acc[mt][1] = mfma(a, b1, acc[mt][1]);
      }
    }
#pragma unroll
    for (int n = 0; n < 2; ++n) {
      const int col = (2 * w + n) * 16 + c;
      const float bv = bm1[col];
#pragma unroll
      for (int mt = 0; mt < 4; ++mt)
#pragma unroll
        for (int r = 0; r < 4; ++r) {
          const int row = mt * 16 + g * 4 + r;
          float v = fmaxf(acc[mt][n][r] + bv, 0.f);
          *(unsigned short*)(sm + B_AT + row * 512 +
                             ((col * 2) ^ ((row & 7) << 4))) = f2bf(v);
        }
    }
  }
  __syncthreads();

  // B4: mean = m1 @ Wm2 + bm2 -> out
  {
    const int mh = w >> 2, nt = w & 3;
    f32x4 acc[2] = {};
#pragma unroll
    for (int kt = 0; kt < 8; ++kt) {
      short8 b = ldfrag(wf, WM2_OFF, nt, kt, 8, lane);
#pragma unroll
      for (int m2 = 0; m2 < 2; ++m2) {
        const int row = (mh * 2 + m2) * 16 + c;
        short8 a = *(const short8*)(sm + B_AT + row * 512 +
                                    ((kt * 64 + g * 16) ^ ((row & 7) << 4)));
        acc[m2] = mfma(a, b, acc[m2]);
      }
    }
    const float bv = bm2[nt * 16 + c];
#pragma unroll
    for (int m2 = 0; m2 < 2; ++m2)
#pragma unroll
      for (int r = 0; r < 4; ++r) {
        const int row = (mh * 2 + m2) * 16 + g * 4 + r;
        out[(blk * 8 + (row >> 3)) * 512 + (row & 7) * 64 + nt * 16 + c] = acc[m2][r] + bv;
      }
  }
  __syncthreads();

  // B5: l1 = relu(hidden @ Wl1 + bl1) -> B_AT (m1 dead)
  {
    f32x4 acc[4][2] = {};
#pragma unroll
    for (int kt = 0; kt < 8; ++kt) {
      short8 b0 = ldfrag(wf, WL1_OFF, 2 * w, kt, 8, lane);
      short8 b1 = ldfrag(wf, WL1_OFF, 2 * w + 1, kt, 8, lane);
#pragma unroll
      for (int mt = 0; mt < 4; ++mt) {
        const int row = mt * 16 + c;
        short8 a = *(const short8*)(sm + B_H + row * 512 +
                                    ((kt * 64 + g * 16) ^ ((row & 7) << 4)));
        acc[mt][0] = mfma(a, b0, acc[mt][0]);
        acc[mt][1] = mfma(a, b1, acc[mt][1]);
      }
    }
#pragma unroll
    for (int n = 0; n < 2; ++n) {
      const int col = (2 * w + n) * 16 + c;
      const float bv = bl1[col];
#pragma unroll
      for (int mt = 0; mt < 4; ++mt)
#pragma unroll
        for (int r = 0; r < 4; ++r) {
          const int row = mt * 16 + g * 4 + r;
          float v = fmaxf(acc[mt][n][r] + bv, 0.f);
          *(unsigned short*)(sm + B_AT + row * 512 +
                             ((col * 2) ^ ((row & 7) << 4))) = f2bf(v);
        }
    }
  }
  __syncthreads();

  // B6: logvar = clip(l1 @ Wl2 + bl2, -10, 0) -> out
  {
    const int mh = w >> 2, nt = w & 3;
    f32x4 acc[2] = {};
#pragma unroll
    for (int kt = 0; kt < 8; ++kt) {
      short8 b = ldfrag(wf, WL2_OFF, nt, kt, 8, lane);
#pragma unroll
      for (int m2 = 0; m2 < 2; ++m2) {
        const int row = (mh * 2 + m2) * 16 + c;
        short8 a = *(const short8*)(sm + B_AT + row * 512 +
                                    ((kt * 64 + g * 16) ^ ((row & 7) << 4)));
        acc[m2] = mfma(a, b, acc[m2]);
      }
    }
    const float bv = bl2[nt * 16 + c];
#pragma unroll
    for (int m2 = 0; m2 < 2; ++m2)
#pragma unroll
      for (int r = 0; r < 4; ++r) {
        const int row = (mh * 2 + m2) * 16 + g * 4 + r;
        float v = acc[m2][r] + bv;
        v = fminf(fmaxf(v, -10.f), 0.f);
        out[2097152 + (blk * 8 + (row >> 3)) * 512 + (row & 7) * 64 + nt * 16 + c] = v;
      }
  }
}

extern "C" void kernel_launch(void* const* d_in, const int* in_sizes, int n_in,
                              void* d_out, int out_size, void* d_ws, size_t ws_size,
                              hipStream_t stream) {
  const float* entities    = (const float*)d_in[0];
  const int*   entity_mask = (const int*)d_in[1];
  const int*   obs_mask    = (const int*)d_in[2];
  const float* acts        = (const float*)d_in[3];
  const float* We   = (const float*)d_in[4];
  const float* be   = (const float*)d_in[5];
  const float* Wa   = (const float*)d_in[6];
  const float* Win  = (const float*)d_in[7];
  const float* Wout = (const float*)d_in[8];
  const float* bout = (const float*)d_in[9];
  const float* Wm1  = (const float*)d_in[10];
  const float* bm1  = (const float*)d_in[11];
  const float* Wm2  = (const float*)d_in[12];
  const float* bm2  = (const float*)d_in[13];
  const float* Wl1  = (const float*)d_in[14];
  const float* bl1  = (const float*)d_in[15];
  const float* Wl2  = (const float*)d_in[16];
  const float* bl2  = (const float*)d_in[17];
  unsigned short* wf = (unsigned short*)d_ws;
  unsigned short* attn_g = wf + ATTN_OFF;

  prep_frag<<<dim3(16, 9), 512, 0, stream>>>(We, Win, Wout, Wm1, Wm2, Wl1, Wl2, wf);

  hipFuncSetAttribute((const void*)front_kernel,
                      hipFuncAttributeMaxDynamicSharedMemorySize, LDS_F);
  hipFuncSetAttribute((const void*)back_kernel,
                      hipFuncAttributeMaxDynamicSharedMemorySize, LDS_B);

  front_kernel<<<4096, 512, LDS_F, stream>>>(entities, obs_mask, acts, Wa, be, wf, attn_g);
  back_kernel<<<512, 512, LDS_B, stream>>>(entity_mask, bout, bm1, bm2, bl1, bl2,
                                           wf, attn_g, (float*)d_out);
}